// Round 16
// baseline (3086.759 us; speedup 1.0000x reference)
//
#include <hip/hip_runtime.h>
#include <hip/hip_bf16.h>

// GAT attention aggregator. R16 = ABLATION ROUND: template<PH> phase-marginal
// measurement (REPS=8) + the real R13 kernel (best 125.2us) writing d_out
// last. PH=1 stage | 2 +score | 3 +softmax | 4 +agg | 5 +final(sink).
// Global loads laundered per-rep (asm volatile) to defeat cross-rep CSE;
// sink forces liveness; ablation output goes to d_ws scratch.

#define BB 20000
#define NN 32
#define DD 128
#define HH 256
#define OO 128
#define MB 4
#define ROWS 144
#define AG0 132

typedef __bf16 bf16x8 __attribute__((ext_vector_type(8)));
typedef __bf16 bf16x4 __attribute__((ext_vector_type(4)));
typedef float f32x4 __attribute__((ext_vector_type(4)));

__global__ void prep_weights(const float* __restrict__ Watt,
                             const float* __restrict__ Wfcx,
                             const float* __restrict__ Wfcn,
                             __bf16* __restrict__ WaT,
                             __bf16* __restrict__ WcT) {
    int idx = blockIdx.x * 256 + threadIdx.x;
    int half = idx >> 15;
    int j = idx & 32767;
    int c = j >> 7, k = j & 127;
    if (half == 0) {
        WaT[j] = (__bf16)Watt[k * HH + c];
    } else {
        float wv = (c < OO) ? Wfcx[k * OO + c] : Wfcn[k * OO + (c - OO)];
        WcT[j] = (__bf16)wv;
    }
}

// ---------------- ablation kernel ----------------
template<int PH, int REPS>
__launch_bounds__(256, 4)
__global__ void gat_abl(const float* __restrict__ x,
                        const float* __restrict__ neibs,
                        const float* __restrict__ a,
                        const __bf16* __restrict__ WaT,
                        const __bf16* __restrict__ WcT,
                        float* __restrict__ sinkbuf) {
    __shared__ __bf16 rowsS[ROWS * 128];
    __shared__ float e_part[4][ROWS];
    __shared__ float att_s[MB][NN];

    const int tid = threadIdx.x;
    const int w   = tid >> 6;
    const int l   = tid & 63;
    const int lr  = l & 15;
    const int lg  = l >> 4;
    const int b0  = blockIdx.x * MB;
    char* rbase = (char*)rowsS;

    const int stbase = (tid >> 5) * 256 + ((8 * (tid & 31)) ^ ((tid >> 5) << 4));
    int abase[4];
#pragma unroll
    for (int ks = 0; ks < 4; ++ks)
        abase[ks] = lr * 256 + ((ks * 64 + lg * 16) ^ ((lr & 7) << 4));

    // W_att panel resident across reps (matches real kernel's one-time load)
    bf16x8 bw[4][4];
#pragma unroll
    for (int c4 = 0; c4 < 4; ++c4)
#pragma unroll
        for (int ks = 0; ks < 4; ++ks)
            bw[c4][ks] = *(const bf16x8*)(WaT + ((w * 4 + c4) * 16 + lr) * 128 + ks * 32 + lg * 8);

    float sink = 0.f;

    for (int rep = 0; rep < REPS; ++rep) {
        // launder base pointers so rep-invariant global loads can't CSE
        unsigned long long npq = (unsigned long long)(neibs + (size_t)b0 * NN * DD);
        unsigned long long xpq = (unsigned long long)(x + (size_t)b0 * DD);
        asm volatile("" : "+v"(npq), "+v"(xpq));
        const float4* np4 = (const float4*)npq;
        const float4* xp4 = (const float4*)xpq;

        // ---- phase 1: stage ----
#pragma unroll
        for (int it = 0; it < 16; ++it) {
            float4 v = np4[it * 256 + tid];
            bf16x4 s = { (__bf16)v.x, (__bf16)v.y, (__bf16)v.z, (__bf16)v.w };
            *(bf16x4*)(rbase + stbase + it * 2048) = s;
        }
        if (tid < 128) {
            float4 v = xp4[tid];
            bf16x4 s = { (__bf16)v.x, (__bf16)v.y, (__bf16)v.z, (__bf16)v.w };
            *(bf16x4*)(rbase + stbase + 32768) = s;
        }
        __syncthreads();                          // B1

        // ---- phase 2: score (swapped operands) ----
        if constexpr (PH >= 2) {
            float cN[4][4];
#pragma unroll
            for (int c4 = 0; c4 < 4; ++c4)
#pragma unroll
                for (int i = 0; i < 4; ++i)
                    cN[c4][i] = a[HH + (w * 4 + c4) * 16 + 4 * lg + i];
#pragma unroll
            for (int rt = 0; rt < 8; ++rt) {
                bf16x8 af[4];
#pragma unroll
                for (int ks = 0; ks < 4; ++ks)
                    af[ks] = *(const bf16x8*)(rbase + abase[ks] + rt * 4096);
                f32x4 acc[4];
#pragma unroll
                for (int c4 = 0; c4 < 4; ++c4) acc[c4] = (f32x4){0.f, 0.f, 0.f, 0.f};
#pragma unroll
                for (int ks = 0; ks < 4; ++ks)
#pragma unroll
                    for (int c4 = 0; c4 < 4; ++c4)
                        acc[c4] = __builtin_amdgcn_mfma_f32_16x16x32_bf16(bw[c4][ks], af[ks], acc[c4], 0, 0, 0);
                float ep = 0.f;
#pragma unroll
                for (int c4 = 0; c4 < 4; ++c4)
#pragma unroll
                    for (int i = 0; i < 4; ++i) {
                        float v = acc[c4][i];
                        ep = fmaf(cN[c4][i], fmaxf(v, 0.01f * v), ep);
                    }
                ep += __shfl_xor(ep, 16);
                ep += __shfl_xor(ep, 32);
                if (l < 16) e_part[w][rt * 16 + l] = ep;
            }
            // peeled x tile
#pragma unroll
            for (int c4 = 0; c4 < 4; ++c4)
#pragma unroll
                for (int i = 0; i < 4; ++i)
                    cN[c4][i] = a[(w * 4 + c4) * 16 + 4 * lg + i];
            bf16x8 af[4];
#pragma unroll
            for (int ks = 0; ks < 4; ++ks)
                af[ks] = *(const bf16x8*)(rbase + abase[ks] + 32768);
            f32x4 acc[4];
#pragma unroll
            for (int c4 = 0; c4 < 4; ++c4) acc[c4] = (f32x4){0.f, 0.f, 0.f, 0.f};
#pragma unroll
            for (int ks = 0; ks < 4; ++ks)
#pragma unroll
                for (int c4 = 0; c4 < 4; ++c4)
                    acc[c4] = __builtin_amdgcn_mfma_f32_16x16x32_bf16(bw[c4][ks], af[ks], acc[c4], 0, 0, 0);
            float ep = 0.f;
#pragma unroll
            for (int c4 = 0; c4 < 4; ++c4)
#pragma unroll
                for (int i = 0; i < 4; ++i) {
                    float v = acc[c4][i];
                    ep = fmaf(cN[c4][i], fmaxf(v, 0.01f * v), ep);
                }
            ep += __shfl_xor(ep, 16);
            ep += __shfl_xor(ep, 32);
            if (l < 16) e_part[w][128 + l] = ep;
        }
        __syncthreads();                          // B2

        // ---- phase 3: softmax ----
        if constexpr (PH >= 3) {
            if (tid < 128) {
                const int bloc = tid >> 5;
                const int nloc = tid & 31;
                float sn = e_part[0][tid] + e_part[1][tid] + e_part[2][tid] + e_part[3][tid];
                float sx = e_part[0][128 + bloc] + e_part[1][128 + bloc] +
                           e_part[2][128 + bloc] + e_part[3][128 + bloc];
                float e = sx + sn;
                e = (e > 0.f) ? e : 0.2f * e;
                float mx = e;
#pragma unroll
                for (int m = 16; m >= 1; m >>= 1) mx = fmaxf(mx, __shfl_xor(mx, m, 32));
                float ex = __expf(e - mx);
                float sum = ex;
#pragma unroll
                for (int m = 16; m >= 1; m >>= 1) sum += __shfl_xor(sum, m, 32);
                att_s[bloc][nloc] = ex / sum;
            }
        }
        __syncthreads();                          // B3

        // ---- phase 4: aggregation ----
        if constexpr (PH >= 4) {
            const int half = l >> 5, li = l & 31;
            const int agbase = w * 8192 + 256 * half + ((8 * li) ^ (half << 4));
            float ag[4] = {0.f, 0.f, 0.f, 0.f};
#pragma unroll
            for (int i = 0; i < 16; ++i) {
                float wv = att_s[w][2 * i + half];
                bf16x4 v = *(const bf16x4*)(rbase + (agbase ^ ((2 * i & 7) << 4)) + 512 * i);
#pragma unroll
                for (int j = 0; j < 4; ++j) ag[j] = fmaf(wv, (float)v[j], ag[j]);
            }
#pragma unroll
            for (int j = 0; j < 4; ++j) ag[j] += __shfl_xor(ag[j], 32);
            if (half == 0) {
                int row = AG0 + w;
                int off = row * 256 + ((8 * li) ^ ((row & 7) << 4));
                bf16x4 s = { (__bf16)ag[0], (__bf16)ag[1], (__bf16)ag[2], (__bf16)ag[3] };
                *(bf16x4*)(rbase + off) = s;
            }
        }
        __syncthreads();                          // B4

        // ---- phase 5: final matmul (accumulators -> sink; no store) ----
        if constexpr (PH >= 5) {
            bf16x8 bff[4][4];
#pragma unroll
            for (int c4 = 0; c4 < 4; ++c4)
#pragma unroll
                for (int ks = 0; ks < 4; ++ks)
                    bff[c4][ks] = *(const bf16x8*)(WcT + ((w * 4 + c4) * 16 + lr) * 128 + ks * 32 + lg * 8);
            bf16x8 af[4];
#pragma unroll
            for (int ks = 0; ks < 4; ++ks)
                af[ks] = *(const bf16x8*)(rbase + abase[ks] + 32768);
            f32x4 acc[4];
#pragma unroll
            for (int c4 = 0; c4 < 4; ++c4) acc[c4] = (f32x4){0.f, 0.f, 0.f, 0.f};
#pragma unroll
            for (int ks = 0; ks < 4; ++ks)
#pragma unroll
                for (int c4 = 0; c4 < 4; ++c4)
                    acc[c4] = __builtin_amdgcn_mfma_f32_16x16x32_bf16(af[ks], bff[c4][ks], acc[c4], 0, 0, 0);
#pragma unroll
            for (int c4 = 0; c4 < 4; ++c4)
                sink += acc[c4][0] + acc[c4][1] + acc[c4][2] + acc[c4][3];
        }
    }

    // keep all LDS state observable
    sink += (float)rowsS[(tid * 37) & 18431];
    sink += e_part[w][(tid * 5) % ROWS];
    sink += att_s[w & 3][l & 31];
    sinkbuf[((blockIdx.x << 8) | tid) & 4095] = sink;
}

// ---------------- real kernel: R13 verbatim (best, 125.2us) ----------------
__launch_bounds__(256, 4)
__global__ void gat_fused(const float* __restrict__ x,
                          const float* __restrict__ neibs,
                          const float* __restrict__ a,
                          const __bf16* __restrict__ WaT,
                          const __bf16* __restrict__ WcT,
                          float* __restrict__ out) {
    __shared__ __bf16 rowsS[ROWS * 128];
    __shared__ float e_part[4][ROWS];
    __shared__ float att_s[MB][NN];

    {
        const unsigned bid = blockIdx.x;
        if (bid < 1280) {
            const unsigned k = (bid * 2654435761u) >> 30;
            for (unsigned i = 0; i < k; ++i)
                __builtin_amdgcn_s_sleep(40);
        }
    }

    const int tid = threadIdx.x;
    const int w   = tid >> 6;
    const int l   = tid & 63;
    const int lr  = l & 15;
    const int lg  = l >> 4;
    const int b0  = blockIdx.x * MB;
    char* rbase = (char*)rowsS;

    const int stbase = (tid >> 5) * 256 + ((8 * (tid & 31)) ^ ((tid >> 5) << 4));
    int abase[4];
#pragma unroll
    for (int ks = 0; ks < 4; ++ks)
        abase[ks] = lr * 256 + ((ks * 64 + lg * 16) ^ ((lr & 7) << 4));

    {
        const float4* np4 = (const float4*)(neibs + (size_t)b0 * NN * DD);
#pragma unroll
        for (int it = 0; it < 16; ++it) {
            float4 v = np4[it * 256 + tid];
            bf16x4 s = { (__bf16)v.x, (__bf16)v.y, (__bf16)v.z, (__bf16)v.w };
            *(bf16x4*)(rbase + stbase + it * 2048) = s;
        }
        if (tid < 128) {
            float4 v = ((const float4*)(x + (size_t)b0 * DD))[tid];
            bf16x4 s = { (__bf16)v.x, (__bf16)v.y, (__bf16)v.z, (__bf16)v.w };
            *(bf16x4*)(rbase + stbase + 32768) = s;
        }
    }

    bf16x8 bw[4][4];
    float cN[4][4];
#pragma unroll
    for (int c4 = 0; c4 < 4; ++c4) {
        int col = (w * 4 + c4) * 16 + lr;
#pragma unroll
        for (int ks = 0; ks < 4; ++ks)
            bw[c4][ks] = *(const bf16x8*)(WaT + col * 128 + ks * 32 + lg * 8);
#pragma unroll
        for (int i = 0; i < 4; ++i)
            cN[c4][i] = a[HH + (w * 4 + c4) * 16 + 4 * lg + i];
    }

    __syncthreads();

#pragma unroll
    for (int rt = 0; rt < 8; ++rt) {
        bf16x8 af[4];
#pragma unroll
        for (int ks = 0; ks < 4; ++ks)
            af[ks] = *(const bf16x8*)(rbase + abase[ks] + rt * 4096);
        f32x4 acc[4];
#pragma unroll
        for (int c4 = 0; c4 < 4; ++c4) acc[c4] = (f32x4){0.f, 0.f, 0.f, 0.f};
#pragma unroll
        for (int ks = 0; ks < 4; ++ks)
#pragma unroll
            for (int c4 = 0; c4 < 4; ++c4)
                acc[c4] = __builtin_amdgcn_mfma_f32_16x16x32_bf16(bw[c4][ks], af[ks], acc[c4], 0, 0, 0);
        float ep = 0.f;
#pragma unroll
        for (int c4 = 0; c4 < 4; ++c4)
#pragma unroll
            for (int i = 0; i < 4; ++i) {
                float v = acc[c4][i];
                ep = fmaf(cN[c4][i], fmaxf(v, 0.01f * v), ep);
            }
        ep += __shfl_xor(ep, 16);
        ep += __shfl_xor(ep, 32);
        if (l < 16) e_part[w][rt * 16 + l] = ep;
    }
    {
#pragma unroll
        for (int c4 = 0; c4 < 4; ++c4)
#pragma unroll
            for (int i = 0; i < 4; ++i)
                cN[c4][i] = a[(w * 4 + c4) * 16 + 4 * lg + i];
        bf16x8 af[4];
#pragma unroll
        for (int ks = 0; ks < 4; ++ks)
            af[ks] = *(const bf16x8*)(rbase + abase[ks] + 32768);
        f32x4 acc[4];
#pragma unroll
        for (int c4 = 0; c4 < 4; ++c4) acc[c4] = (f32x4){0.f, 0.f, 0.f, 0.f};
#pragma unroll
        for (int ks = 0; ks < 4; ++ks)
#pragma unroll
            for (int c4 = 0; c4 < 4; ++c4)
                acc[c4] = __builtin_amdgcn_mfma_f32_16x16x32_bf16(bw[c4][ks], af[ks], acc[c4], 0, 0, 0);
        float ep = 0.f;
#pragma unroll
        for (int c4 = 0; c4 < 4; ++c4)
#pragma unroll
            for (int i = 0; i < 4; ++i) {
                float v = acc[c4][i];
                ep = fmaf(cN[c4][i], fmaxf(v, 0.01f * v), ep);
            }
        ep += __shfl_xor(ep, 16);
        ep += __shfl_xor(ep, 32);
        if (l < 16) e_part[w][128 + l] = ep;
    }
    __syncthreads();

    if (tid < 128) {
        const int bloc = tid >> 5;
        const int nloc = tid & 31;
        float sn = e_part[0][tid] + e_part[1][tid] + e_part[2][tid] + e_part[3][tid];
        float sx = e_part[0][128 + bloc] + e_part[1][128 + bloc] +
                   e_part[2][128 + bloc] + e_part[3][128 + bloc];
        float e = sx + sn;
        e = (e > 0.f) ? e : 0.2f * e;
        float mx = e;
#pragma unroll
        for (int m = 16; m >= 1; m >>= 1) mx = fmaxf(mx, __shfl_xor(mx, m, 32));
        float ex = __expf(e - mx);
        float sum = ex;
#pragma unroll
        for (int m = 16; m >= 1; m >>= 1) sum += __shfl_xor(sum, m, 32);
        att_s[bloc][nloc] = ex / sum;
    }
    __syncthreads();

    bf16x8 bff[4][4];
#pragma unroll
    for (int c4 = 0; c4 < 4; ++c4)
#pragma unroll
        for (int ks = 0; ks < 4; ++ks)
            bff[c4][ks] = *(const bf16x8*)(WcT + ((w * 4 + c4) * 16 + lr) * 128 + ks * 32 + lg * 8);

    {
        const int half = l >> 5, li = l & 31;
        const int agbase = w * 8192 + 256 * half + ((8 * li) ^ (half << 4));
        float ag[4] = {0.f, 0.f, 0.f, 0.f};
#pragma unroll
        for (int i = 0; i < 16; ++i) {
            float wv = att_s[w][2 * i + half];
            bf16x4 v = *(const bf16x4*)(rbase + (agbase ^ ((2 * i & 7) << 4)) + 512 * i);
#pragma unroll
            for (int j = 0; j < 4; ++j) ag[j] = fmaf(wv, (float)v[j], ag[j]);
        }
#pragma unroll
        for (int j = 0; j < 4; ++j) ag[j] += __shfl_xor(ag[j], 32);
        if (half == 0) {
            int row = AG0 + w;
            int off = row * 256 + ((8 * li) ^ ((row & 7) << 4));
            bf16x4 s = { (__bf16)ag[0], (__bf16)ag[1], (__bf16)ag[2], (__bf16)ag[3] };
            *(bf16x4*)(rbase + off) = s;
        }
    }
    __syncthreads();

    {
        bf16x8 af[4];
#pragma unroll
        for (int ks = 0; ks < 4; ++ks)
            af[ks] = *(const bf16x8*)(rbase + abase[ks] + 32768);
        f32x4 acc[4];
#pragma unroll
        for (int c4 = 0; c4 < 4; ++c4) acc[c4] = (f32x4){0.f, 0.f, 0.f, 0.f};
#pragma unroll
        for (int ks = 0; ks < 4; ++ks)
#pragma unroll
            for (int c4 = 0; c4 < 4; ++c4)
                acc[c4] = __builtin_amdgcn_mfma_f32_16x16x32_bf16(af[ks], bff[c4][ks], acc[c4], 0, 0, 0);
#pragma unroll
        for (int c4 = 0; c4 < 4; ++c4) {
            int col = (w * 4 + c4) * 16 + lr;
#pragma unroll
            for (int reg = 0; reg < 4; ++reg) {
                int i = lg * 4 + reg;
                bool doit = (col < 128) ? (i < 4) : (i >= 4 && i < 8);
                if (doit) {
                    float v = fmaxf(acc[c4][reg], 0.f);
                    out[(size_t)(b0 + (i & 3)) * 256 + col] = v;
                }
            }
        }
    }
}

extern "C" void kernel_launch(void* const* d_in, const int* in_sizes, int n_in,
                              void* d_out, int out_size, void* d_ws, size_t ws_size,
                              hipStream_t stream) {
    const float* x    = (const float*)d_in[0];
    const float* nb   = (const float*)d_in[1];
    const float* Watt = (const float*)d_in[2];
    const float* Wfcx = (const float*)d_in[3];
    const float* Wfcn = (const float*)d_in[4];
    const float* a    = (const float*)d_in[5];
    __bf16* WaT = (__bf16*)d_ws;
    __bf16* WcT = WaT + 32768;
    float* sinkb = (float*)((char*)d_ws + 131072);   // 16 KB scratch window
    float* o = (float*)d_out;

    prep_weights<<<256, 256, 0, stream>>>(Watt, Wfcx, Wfcn, WaT, WcT);
    gat_abl<1, 8><<<BB / MB, 256, 0, stream>>>(x, nb, a, WaT, WcT, sinkb);
    gat_abl<2, 8><<<BB / MB, 256, 0, stream>>>(x, nb, a, WaT, WcT, sinkb);
    gat_abl<3, 8><<<BB / MB, 256, 0, stream>>>(x, nb, a, WaT, WcT, sinkb);
    gat_abl<4, 8><<<BB / MB, 256, 0, stream>>>(x, nb, a, WaT, WcT, sinkb);
    gat_abl<5, 8><<<BB / MB, 256, 0, stream>>>(x, nb, a, WaT, WcT, sinkb);
    gat_fused<<<BB / MB, 256, 0, stream>>>(x, nb, a, WaT, WcT, o);
}

// Round 17
// 274.308 us; speedup vs baseline: 11.2529x; 11.2529x over previous
//
#include <hip/hip_runtime.h>
#include <hip/hip_bf16.h>

// GAT attention aggregator, fused. B=20000, N=32, D=128, H=256, O=128.
// R17: NO LDS STAGING. Score MFMA B-fragments load straight from global f32
// (swapped operands make the fragment = 32B contiguous row chunks), cvt to
// bf16 in-reg. Aggregation re-reads the tile from L2 as f32 (better
// numerics). LDS = e_part + agg rows only (~3.5 KB); 2 barriers (was 4).
// Ablation R16 showed staging ~= 1/3 of the wall and phases serialize.

#define BB 20000
#define NN 32
#define DD 128
#define HH 256
#define OO 128
#define MB 4

typedef __bf16 bf16x8 __attribute__((ext_vector_type(8)));
typedef __bf16 bf16x2 __attribute__((ext_vector_type(2)));
typedef float f32x4 __attribute__((ext_vector_type(4)));

__device__ __forceinline__ bf16x8 cvt8(float4 u, float4 v) {
    return (bf16x8){ (__bf16)u.x, (__bf16)u.y, (__bf16)u.z, (__bf16)u.w,
                     (__bf16)v.x, (__bf16)v.y, (__bf16)v.z, (__bf16)v.w };
}

__global__ void prep_weights(const float* __restrict__ Watt,
                             const float* __restrict__ Wfcx,
                             const float* __restrict__ Wfcn,
                             __bf16* __restrict__ WaT,
                             __bf16* __restrict__ WcT) {
    int idx = blockIdx.x * 256 + threadIdx.x;   // 0..65535
    int half = idx >> 15;
    int j = idx & 32767;
    int c = j >> 7, k = j & 127;
    if (half == 0) {
        WaT[j] = (__bf16)Watt[k * HH + c];       // WaT[h][k] = W_att[k][h]
    } else {
        float wv = (c < OO) ? Wfcx[k * OO + c] : Wfcn[k * OO + (c - OO)];
        WcT[j] = (__bf16)wv;                     // WcT[c][k]
    }
}

__launch_bounds__(256, 4)
__global__ void gat_fused(const float* __restrict__ x,
                          const float* __restrict__ neibs,
                          const float* __restrict__ a,
                          const __bf16* __restrict__ WaT,
                          const __bf16* __restrict__ WcT,
                          float* __restrict__ out) {
    __shared__ float e_part[4][144];             // 2,304 B
    __shared__ __bf16 aggL[4 * 136];             // 1,088 B (+16B row pad)

    const int tid = threadIdx.x;
    const int w   = tid >> 6;      // wave 0..3 == local node
    const int l   = tid & 63;
    const int lr  = l & 15;
    const int lg  = l >> 4;
    const int b0  = blockIdx.x * MB;
    const float* nb = neibs + (size_t)b0 * NN * DD;

    // ---- W_att panel (A-operand, L2-resident) + a-coefs ----
    bf16x8 bw[4][4];
    float cN[4][4];
#pragma unroll
    for (int c4 = 0; c4 < 4; ++c4) {
        int col = (w * 4 + c4) * 16 + lr;
#pragma unroll
        for (int ks = 0; ks < 4; ++ks)
            bw[c4][ks] = *(const bf16x8*)(WaT + col * 128 + ks * 32 + lg * 8);
#pragma unroll
        for (int i = 0; i < 4; ++i)
            cN[c4][i] = a[HH + (w * 4 + c4) * 16 + 4 * lg + i];
    }

    // ---- score (swapped): acc = W^T-tile x R-rows, R-frags straight from HBM ----
    // B-frag: lane lr = row rt*16+lr, k = ks*32 + lg*8 + j  -> 32B row chunk.
#pragma unroll
    for (int rt = 0; rt < 8; ++rt) {
        bf16x8 af[4];
#pragma unroll
        for (int ks = 0; ks < 4; ++ks) {
            const float* p = nb + (rt * 16 + lr) * 128 + ks * 32 + lg * 8;
            af[ks] = cvt8(*(const float4*)p, *(const float4*)(p + 4));
        }
        f32x4 acc[4];
#pragma unroll
        for (int c4 = 0; c4 < 4; ++c4) acc[c4] = (f32x4){0.f, 0.f, 0.f, 0.f};
#pragma unroll
        for (int ks = 0; ks < 4; ++ks)
#pragma unroll
            for (int c4 = 0; c4 < 4; ++c4)
                acc[c4] = __builtin_amdgcn_mfma_f32_16x16x32_bf16(bw[c4][ks], af[ks], acc[c4], 0, 0, 0);
        float ep = 0.f;
#pragma unroll
        for (int c4 = 0; c4 < 4; ++c4)
#pragma unroll
            for (int i = 0; i < 4; ++i) {
                float v = acc[c4][i];
                ep = fmaf(cN[c4][i], fmaxf(v, 0.01f * v), ep);
            }
        ep += __shfl_xor(ep, 16);
        ep += __shfl_xor(ep, 32);
        if (l < 16) e_part[w][rt * 16 + l] = ep;
    }
    // peeled x-tile: rows b0..b0+3 (lanes lr>=4 clamp; their results are unread)
    {
#pragma unroll
        for (int c4 = 0; c4 < 4; ++c4)
#pragma unroll
            for (int i = 0; i < 4; ++i)
                cN[c4][i] = a[(w * 4 + c4) * 16 + 4 * lg + i];
        const float* xp = x + (size_t)(b0 + (lr & 3)) * 128;
        bf16x8 af[4];
#pragma unroll
        for (int ks = 0; ks < 4; ++ks) {
            const float* p = xp + ks * 32 + lg * 8;
            af[ks] = cvt8(*(const float4*)p, *(const float4*)(p + 4));
        }
        f32x4 acc[4];
#pragma unroll
        for (int c4 = 0; c4 < 4; ++c4) acc[c4] = (f32x4){0.f, 0.f, 0.f, 0.f};
#pragma unroll
        for (int ks = 0; ks < 4; ++ks)
#pragma unroll
            for (int c4 = 0; c4 < 4; ++c4)
                acc[c4] = __builtin_amdgcn_mfma_f32_16x16x32_bf16(bw[c4][ks], af[ks], acc[c4], 0, 0, 0);
        float ep = 0.f;
#pragma unroll
        for (int c4 = 0; c4 < 4; ++c4)
#pragma unroll
            for (int i = 0; i < 4; ++i) {
                float v = acc[c4][i];
                ep = fmaf(cN[c4][i], fmaxf(v, 0.01f * v), ep);
            }
        ep += __shfl_xor(ep, 16);
        ep += __shfl_xor(ep, 32);
        if (l < 16) e_part[w][128 + l] = ep;      // only 128..131 are read
    }
    __syncthreads();                              // B1: e_part complete

    // ---- in-wave softmax: wave w handles node w (32-lane halves duplicate) ----
    float att;
    {
        const int nl = l & 31;
        const int idx = w * 32 + nl;
        const int xr = 128 + w;
        float e = e_part[0][idx] + e_part[1][idx] + e_part[2][idx] + e_part[3][idx]
                + e_part[0][xr]  + e_part[1][xr]  + e_part[2][xr]  + e_part[3][xr];
        e = (e > 0.f) ? e : 0.2f * e;
        float mx = e;
#pragma unroll
        for (int m = 16; m >= 1; m >>= 1) mx = fmaxf(mx, __shfl_xor(mx, m, 32));
        float ex = __expf(e - mx);
        float sum = ex;
#pragma unroll
        for (int m = 16; m >= 1; m >>= 1) sum += __shfl_xor(sum, m, 32);
        att = ex / sum;
    }

    // WcT panel loads issue here — L2 latency hides under aggregation
    bf16x8 bff[4][4];
#pragma unroll
    for (int c4 = 0; c4 < 4; ++c4)
#pragma unroll
        for (int ks = 0; ks < 4; ++ks)
            bff[c4][ks] = *(const bf16x8*)(WcT + ((w * 4 + c4) * 16 + lr) * 128 + ks * 32 + lg * 8);

    // ---- aggregation: wave w = node w; lane owns d-pair (2l, 2l+1); L2 reads ----
    {
        const float* rp = nb + (w * 32) * 128 + 2 * l;
        float ag0 = 0.f, ag1 = 0.f;
#pragma unroll 8
        for (int n = 0; n < 32; ++n) {
            float wv = __shfl(att, n);            // lane n holds att[n]
            float2 v = *(const float2*)(rp + n * 128);
            ag0 = fmaf(wv, v.x, ag0);
            ag1 = fmaf(wv, v.y, ag1);
        }
        bf16x2 s = { (__bf16)ag0, (__bf16)ag1 };
        *(bf16x2*)((char*)aggL + w * 272 + 4 * l) = s;
    }
    __syncthreads();                              // B2: agg rows visible

    // ---- final matmul: [x(4); agg(4); dup] (16x128) @ WcT^T, masked store ----
    {
        bf16x8 af[4];
        if (lr < 4) {                             // x rows from global (L2-hot)
            const float* xp = x + (size_t)(b0 + lr) * 128;
#pragma unroll
            for (int ks = 0; ks < 4; ++ks) {
                const float* p = xp + ks * 32 + lg * 8;
                af[ks] = cvt8(*(const float4*)p, *(const float4*)(p + 4));
            }
        } else {                                  // agg rows (and dup for lr>=8)
            const char* ap = (const char*)aggL + ((lr - 4) & 3) * 272;
#pragma unroll
            for (int ks = 0; ks < 4; ++ks)
                af[ks] = *(const bf16x8*)(ap + ks * 64 + lg * 16);
        }
        f32x4 acc[4];
#pragma unroll
        for (int c4 = 0; c4 < 4; ++c4) acc[c4] = (f32x4){0.f, 0.f, 0.f, 0.f};
#pragma unroll
        for (int ks = 0; ks < 4; ++ks)
#pragma unroll
            for (int c4 = 0; c4 < 4; ++c4)
                acc[c4] = __builtin_amdgcn_mfma_f32_16x16x32_bf16(af[ks], bff[c4][ks], acc[c4], 0, 0, 0);
#pragma unroll
        for (int c4 = 0; c4 < 4; ++c4) {
            int col = (w * 4 + c4) * 16 + lr;
#pragma unroll
            for (int reg = 0; reg < 4; ++reg) {
                int i = lg * 4 + reg;             // C row: 0..3 = x, 4..7 = agg
                bool doit = (col < 128) ? (i < 4) : (i >= 4 && i < 8);
                if (doit) {
                    float v = fmaxf(acc[c4][reg], 0.f);
                    out[(size_t)(b0 + (i & 3)) * 256 + col] = v;
                }
            }
        }
    }
}

extern "C" void kernel_launch(void* const* d_in, const int* in_sizes, int n_in,
                              void* d_out, int out_size, void* d_ws, size_t ws_size,
                              hipStream_t stream) {
    const float* x    = (const float*)d_in[0];
    const float* nb   = (const float*)d_in[1];
    const float* Watt = (const float*)d_in[2];
    const float* Wfcx = (const float*)d_in[3];
    const float* Wfcn = (const float*)d_in[4];
    const float* a    = (const float*)d_in[5];
    __bf16* WaT = (__bf16*)d_ws;
    __bf16* WcT = WaT + 32768;
    float* o = (float*)d_out;

    prep_weights<<<256, 256, 0, stream>>>(Watt, Wfcx, Wfcn, WaT, WcT);
    gat_fused<<<BB / MB, 256, 0, stream>>>(x, nb, a, WaT, WcT, o);
}

// Round 18
// 258.836 us; speedup vs baseline: 11.9255x; 1.0598x over previous
//
#include <hip/hip_runtime.h>
#include <hip/hip_bf16.h>

// GAT attention aggregator, fused. B=20000, N=32, D=128, H=256, O=128.
// R18: 2-tile pairing on the R13 skeleton (best 125.2us). 2500 blocks x 2
// consecutive MB=4 tiles. One peeled x-score and ONE full-utilization final
// matmul (A=[x0,agg0,x1,agg1]) per pair; tile1's 16-float4 prefetch is issued
// at softmax0 and stays in flight across lgkmcnt-only LBAR barriers
// (__syncthreads drains vmcnt -> would serialize), landing under agg0.

#define BB 20000
#define NN 32
#define DD 128
#define HH 256
#define OO 128
#define MB 4
#define GRID 2500

typedef __bf16 bf16x8 __attribute__((ext_vector_type(8)));
typedef __bf16 bf16x4 __attribute__((ext_vector_type(4)));
typedef float f32x4 __attribute__((ext_vector_type(4)));

#define LBAR() do { asm volatile("s_waitcnt lgkmcnt(0)" ::: "memory"); \
                    __builtin_amdgcn_s_barrier(); } while (0)

__global__ void prep_weights(const float* __restrict__ Watt,
                             const float* __restrict__ Wfcx,
                             const float* __restrict__ Wfcn,
                             __bf16* __restrict__ WaT,
                             __bf16* __restrict__ WcT) {
    int idx = blockIdx.x * 256 + threadIdx.x;   // 0..65535
    int half = idx >> 15;
    int j = idx & 32767;
    int c = j >> 7, k = j & 127;
    if (half == 0) {
        WaT[j] = (__bf16)Watt[k * HH + c];       // WaT[h][k] = W_att[k][h]
    } else {
        float wv = (c < OO) ? Wfcx[k * OO + c] : Wfcn[k * OO + (c - OO)];
        WcT[j] = (__bf16)wv;                     // WcT[c][k]
    }
}

__launch_bounds__(256, 4)
__global__ void gat_fused(const float* __restrict__ x,
                          const float* __restrict__ neibs,
                          const float* __restrict__ a,
                          const __bf16* __restrict__ WaT,
                          const __bf16* __restrict__ WcT,
                          float* __restrict__ out) {
    __shared__ __bf16 rowsS[128 * 128];          // 32 KB neib tile, XOR-swizzled
    __shared__ __bf16 xagg[16 * 128];            //  4 KB: x0|agg0|x1|agg1
    __shared__ float e_part[4][144];             //  2,304 B
    __shared__ float att_s[4][32];               //    512 B

    const int tid = threadIdx.x;
    const int w   = tid >> 6;      // wave 0..3 (node within current tile)
    const int l   = tid & 63;
    const int lr  = l & 15;
    const int lg  = l >> 4;
    const int g0  = (int)blockIdx.x * 2;         // tiles g0, g0+1
    const int b0  = g0 * MB;                     // nodes b0..b0+7
    char* rb = (char*)rowsS;
    char* xb = (char*)xagg;

    // staging: row = it*8 + (tid>>5); byte (row*256 + 2k) ^ ((row&7)<<4)
    const int stbase = (tid >> 5) * 256 + ((8 * (tid & 31)) ^ ((tid >> 5) << 4));
    int abase[4];
#pragma unroll
    for (int ks = 0; ks < 4; ++ks)
        abase[ks] = lr * 256 + ((ks * 64 + lg * 16) ^ ((lr & 7) << 4));

    // ---- prologue: stage tile0 neibs + ALL 8 x rows (one float4/thread) ----
    {
        const float4* np4 = (const float4*)neibs + (size_t)g0 * 4096;
#pragma unroll
        for (int it = 0; it < 16; ++it) {
            float4 v = np4[it * 256 + tid];
            bf16x4 s = { (__bf16)v.x, (__bf16)v.y, (__bf16)v.z, (__bf16)v.w };
            *(bf16x4*)(rb + stbase + it * 2048) = s;
        }
        float4 v = ((const float4*)x + (size_t)b0 * 32)[tid];
        int r = tid >> 5;                        // x row 0..7
        int xrow = r + ((r >> 2) << 2);          // 0..3 -> 0..3, 4..7 -> 8..11
        unsigned off = xrow * 256 + ((8 * (tid & 31)) ^ ((xrow & 7) << 4));
        bf16x4 s = { (__bf16)v.x, (__bf16)v.y, (__bf16)v.z, (__bf16)v.w };
        *(bf16x4*)(xb + off) = s;
    }

    // ---- W_att panel (A-operand) + neighbor a-coefs (kept for both tiles) ----
    bf16x8 bw[4][4];
    float cN[4][4];
#pragma unroll
    for (int c4 = 0; c4 < 4; ++c4) {
        int col = (w * 4 + c4) * 16 + lr;
#pragma unroll
        for (int ks = 0; ks < 4; ++ks)
            bw[c4][ks] = *(const bf16x8*)(WaT + col * 128 + ks * 32 + lg * 8);
#pragma unroll
        for (int i = 0; i < 4; ++i)
            cN[c4][i] = a[HH + (w * 4 + c4) * 16 + 4 * lg + i];
    }

    // score over neib rows (swapped operands; lane lr owns row rt*16+lr)
    auto SCORE_NEIB = [&]() {
#pragma unroll
        for (int rt = 0; rt < 8; ++rt) {
            bf16x8 af[4];
#pragma unroll
            for (int ks = 0; ks < 4; ++ks)
                af[ks] = *(const bf16x8*)(rb + abase[ks] + rt * 4096);
            f32x4 acc[4];
#pragma unroll
            for (int c4 = 0; c4 < 4; ++c4) acc[c4] = (f32x4){0.f, 0.f, 0.f, 0.f};
#pragma unroll
            for (int ks = 0; ks < 4; ++ks)
#pragma unroll
                for (int c4 = 0; c4 < 4; ++c4)
                    acc[c4] = __builtin_amdgcn_mfma_f32_16x16x32_bf16(bw[c4][ks], af[ks], acc[c4], 0, 0, 0);
            float ep = 0.f;
#pragma unroll
            for (int c4 = 0; c4 < 4; ++c4)
#pragma unroll
                for (int i = 0; i < 4; ++i) {
                    float v = acc[c4][i];
                    ep = fmaf(cN[c4][i], fmaxf(v, 0.01f * v), ep);
                }
            ep += __shfl_xor(ep, 16);
            ep += __shfl_xor(ep, 32);
            if (l < 16) e_part[w][rt * 16 + l] = ep;
        }
    };

    auto SOFTMAX = [&](int xrbase) {             // tid<128; nodes = tid>>5
        if (tid < 128) {
            const int bloc = tid >> 5;
            const int nloc = tid & 31;
            float sn = e_part[0][tid] + e_part[1][tid] + e_part[2][tid] + e_part[3][tid];
            int xr = xrbase + bloc;
            float sx = e_part[0][xr] + e_part[1][xr] + e_part[2][xr] + e_part[3][xr];
            float e = sx + sn;
            e = (e > 0.f) ? e : 0.2f * e;
            float mx = e;
#pragma unroll
            for (int m = 16; m >= 1; m >>= 1) mx = fmaxf(mx, __shfl_xor(mx, m, 32));
            float ex = __expf(e - mx);
            float sum = ex;
#pragma unroll
            for (int m = 16; m >= 1; m >>= 1) sum += __shfl_xor(sum, m, 32);
            att_s[bloc][nloc] = ex / sum;
        }
    };

    auto AGG = [&](int rowbase) {                // wave w = node w; writes xagg
        const int half = l >> 5, li = l & 31;
        const int agbase = w * 8192 + 256 * half + ((8 * li) ^ (half << 4));
        float ag[4] = {0.f, 0.f, 0.f, 0.f};
#pragma unroll
        for (int i = 0; i < 16; ++i) {
            float wv = att_s[w][2 * i + half];
            bf16x4 v = *(const bf16x4*)(rb + (agbase ^ ((2 * i & 7) << 4)) + 512 * i);
#pragma unroll
            for (int j = 0; j < 4; ++j) ag[j] = fmaf(wv, (float)v[j], ag[j]);
        }
#pragma unroll
        for (int j = 0; j < 4; ++j) ag[j] += __shfl_xor(ag[j], 32);
        if (half == 0) {
            int row = rowbase + w;               // (row&7) = 4+w for both tiles
            int off = row * 256 + ((8 * li) ^ ((row & 7) << 4));
            bf16x4 s = { (__bf16)ag[0], (__bf16)ag[1], (__bf16)ag[2], (__bf16)ag[3] };
            *(bf16x4*)(xb + off) = s;
        }
    };

    __syncthreads();                              // B1: tile0 + x rows staged

    SCORE_NEIB();                                 // tile0 -> e_part[w][0..127]
    {   // peeled x-score: ALL 16 xagg rows (x0, junk, x1, junk); junk confined
        float cX[4][4];
#pragma unroll
        for (int c4 = 0; c4 < 4; ++c4)
#pragma unroll
            for (int i = 0; i < 4; ++i)
                cX[c4][i] = a[(w * 4 + c4) * 16 + 4 * lg + i];
        bf16x8 af[4];
#pragma unroll
        for (int ks = 0; ks < 4; ++ks)
            af[ks] = *(const bf16x8*)(xb + abase[ks]);
        f32x4 acc[4];
#pragma unroll
        for (int c4 = 0; c4 < 4; ++c4) acc[c4] = (f32x4){0.f, 0.f, 0.f, 0.f};
#pragma unroll
        for (int ks = 0; ks < 4; ++ks)
#pragma unroll
            for (int c4 = 0; c4 < 4; ++c4)
                acc[c4] = __builtin_amdgcn_mfma_f32_16x16x32_bf16(bw[c4][ks], af[ks], acc[c4], 0, 0, 0);
        float ep = 0.f;
#pragma unroll
        for (int c4 = 0; c4 < 4; ++c4)
#pragma unroll
            for (int i = 0; i < 4; ++i) {
                float v = acc[c4][i];
                ep = fmaf(cX[c4][i], fmaxf(v, 0.01f * v), ep);
            }
        ep += __shfl_xor(ep, 16);
        ep += __shfl_xor(ep, 32);
        if (l < 16) e_part[w][128 + l] = ep;      // rows 0..15 of xagg
    }
    __syncthreads();                              // B2: e_part complete

    SOFTMAX(128);                                 // tile0 (x0 rows 0..3)

    // ---- issue tile1 prefetch; stays in flight across LBARs ----
    float4 pf[16];
    {
        const float4* np1 = (const float4*)neibs + (size_t)(g0 + 1) * 4096;
#pragma unroll
        for (int it = 0; it < 16; ++it) pf[it] = np1[it * 256 + tid];
    }

    LBAR();                                       // B3: att_s visible (lgkm only)
    AGG(4);                                       // agg0 -> xagg rows 4..7
    LBAR();                                       // B4: tile0 neib reads done

    // ---- write tile1 into rowsS (pf lands under agg0) ----
#pragma unroll
    for (int it = 0; it < 16; ++it) {
        bf16x4 s = { (__bf16)pf[it].x, (__bf16)pf[it].y, (__bf16)pf[it].z, (__bf16)pf[it].w };
        *(bf16x4*)(rb + stbase + it * 2048) = s;
    }
    __syncthreads();                              // B5: tile1 staged

    SCORE_NEIB();                                 // tile1 -> e_part[w][0..127]
    __syncthreads();                              // B6

    SOFTMAX(136);                                 // tile1 (x1 rows 8..11)

    // bff panel loads issue here; latency hides under agg1
    bf16x8 bff[4][4];
#pragma unroll
    for (int c4 = 0; c4 < 4; ++c4)
#pragma unroll
        for (int ks = 0; ks < 4; ++ks)
            bff[c4][ks] = *(const bf16x8*)(WcT + ((w * 4 + c4) * 16 + lr) * 128 + ks * 32 + lg * 8);

    __syncthreads();                              // B7: att_s (tile1) visible
    AGG(12);                                      // agg1 -> xagg rows 12..15
    __syncthreads();                              // B8: xagg complete

    // ---- final: [x0,agg0,x1,agg1](16x128) @ WcT^T(128x256), full util ----
    {
        bf16x8 af[4];
#pragma unroll
        for (int ks = 0; ks < 4; ++ks)
            af[ks] = *(const bf16x8*)(xb + abase[ks]);
        f32x4 acc[4];
#pragma unroll
        for (int c4 = 0; c4 < 4; ++c4) acc[c4] = (f32x4){0.f, 0.f, 0.f, 0.f};
#pragma unroll
        for (int ks = 0; ks < 4; ++ks)
#pragma unroll
            for (int c4 = 0; c4 < 4; ++c4)
                acc[c4] = __builtin_amdgcn_mfma_f32_16x16x32_bf16(af[ks], bff[c4][ks], acc[c4], 0, 0, 0);
#pragma unroll
        for (int c4 = 0; c4 < 4; ++c4) {
            int col = (w * 4 + c4) * 16 + lr;
#pragma unroll
            for (int reg = 0; reg < 4; ++reg) {
                int i = lg * 4 + reg;             // A row: i&4 ? agg : x; i>>3 = tile
                bool doit = ((col < 128) == ((i & 4) == 0));
                if (doit) {
                    int orow = b0 + (i & 3) + ((i >> 3) << 2);
                    out[(size_t)orow * 256 + col] = fmaxf(acc[c4][reg], 0.f);
                }
            }
        }
    }
}

extern "C" void kernel_launch(void* const* d_in, const int* in_sizes, int n_in,
                              void* d_out, int out_size, void* d_ws, size_t ws_size,
                              hipStream_t stream) {
    const float* x    = (const float*)d_in[0];
    const float* nb   = (const float*)d_in[1];
    const float* Watt = (const float*)d_in[2];
    const float* Wfcx = (const float*)d_in[3];
    const float* Wfcn = (const float*)d_in[4];
    const float* a    = (const float*)d_in[5];
    __bf16* WaT = (__bf16*)d_ws;
    __bf16* WcT = WaT + 32768;
    float* o = (float*)d_out;

    prep_weights<<<256, 256, 0, stream>>>(Watt, Wfcx, Wfcn, WaT, WcT);
    gat_fused<<<GRID, 256, 0, stream>>>(x, nb, a, WaT, WcT, o);
}

// Round 19
// 163.584 us; speedup vs baseline: 18.8695x; 1.5823x over previous
//
#include <hip/hip_runtime.h>
#include <hip/hip_bf16.h>

// GAT attention aggregator, fused. B=20000, N=32, D=128, H=256, O=128.
// R19: 2-tile pairing WITHOUT register-held prefetch (R18's pf[16] spilled to
// scratch: WRITE_SIZE 215MB). 2500 blocks x 2 consecutive MB=4 tiles, R13's
// proven serial staging per tile. Work deleted per pair: 1 final matmul
// (full 16-row A utilization), 1 x-score pass, 1 bw + 1 bff panel load.
// LDS = 39.7 KB (same 144 rows as R13) -> 4 blocks/CU preserved.

#define BB 20000
#define NN 32
#define DD 128
#define HH 256
#define OO 128
#define MB 4
#define GRID 2500

typedef __bf16 bf16x8 __attribute__((ext_vector_type(8)));
typedef __bf16 bf16x4 __attribute__((ext_vector_type(4)));
typedef float f32x4 __attribute__((ext_vector_type(4)));

__global__ void prep_weights(const float* __restrict__ Watt,
                             const float* __restrict__ Wfcx,
                             const float* __restrict__ Wfcn,
                             __bf16* __restrict__ WaT,
                             __bf16* __restrict__ WcT) {
    int idx = blockIdx.x * 256 + threadIdx.x;   // 0..65535
    int half = idx >> 15;
    int j = idx & 32767;
    int c = j >> 7, k = j & 127;
    if (half == 0) {
        WaT[j] = (__bf16)Watt[k * HH + c];       // WaT[h][k] = W_att[k][h]
    } else {
        float wv = (c < OO) ? Wfcx[k * OO + c] : Wfcn[k * OO + (c - OO)];
        WcT[j] = (__bf16)wv;                     // WcT[c][k]
    }
}

__launch_bounds__(256, 4)
__global__ void gat_fused(const float* __restrict__ x,
                          const float* __restrict__ neibs,
                          const float* __restrict__ a,
                          const __bf16* __restrict__ WaT,
                          const __bf16* __restrict__ WcT,
                          float* __restrict__ out) {
    __shared__ __bf16 rowsS[128 * 128];          // 32 KB neib tile, XOR-swizzled
    __shared__ __bf16 xagg[16 * 128];            //  4 KB: x0|agg0|x1|agg1
    __shared__ float e_part[4][144];             //  2,304 B
    __shared__ float att_s[4][32];               //    512 B

    // ---- round-1 desync (kept from R13) ----
    {
        const unsigned bid = blockIdx.x;
        if (bid < 1024) {
            const unsigned k = (bid * 2654435761u) >> 30;
            for (unsigned i = 0; i < k; ++i)
                __builtin_amdgcn_s_sleep(40);
        }
    }

    const int tid = threadIdx.x;
    const int w   = tid >> 6;      // wave 0..3 == node within current tile
    const int l   = tid & 63;
    const int lr  = l & 15;
    const int lg  = l >> 4;
    const int g0  = (int)blockIdx.x * 2;         // tiles g0, g0+1
    const int b0  = g0 * MB;                     // nodes b0..b0+7
    char* rb = (char*)rowsS;
    char* xb = (char*)xagg;

    // staging: row = it*8 + (tid>>5); byte (row*256 + 2k) ^ ((row&7)<<4)
    const int stbase = (tid >> 5) * 256 + ((8 * (tid & 31)) ^ ((tid >> 5) << 4));
    int abase[4];
#pragma unroll
    for (int ks = 0; ks < 4; ++ks)
        abase[ks] = lr * 256 + ((ks * 64 + lg * 16) ^ ((lr & 7) << 4));

    // ---- prologue: stage tile0 neibs + ALL 8 x rows ----
    {
        const float4* np4 = (const float4*)neibs + (size_t)g0 * 4096;
#pragma unroll
        for (int it = 0; it < 16; ++it) {
            float4 v = np4[it * 256 + tid];
            bf16x4 s = { (__bf16)v.x, (__bf16)v.y, (__bf16)v.z, (__bf16)v.w };
            *(bf16x4*)(rb + stbase + it * 2048) = s;
        }
        float4 v = ((const float4*)x + (size_t)b0 * 32)[tid];
        int r = tid >> 5;                        // x row 0..7
        int xrow = r + ((r >> 2) << 2);          // 0..3 -> 0..3, 4..7 -> 8..11
        unsigned off = xrow * 256 + ((8 * (tid & 31)) ^ ((xrow & 7) << 4));
        bf16x4 s = { (__bf16)v.x, (__bf16)v.y, (__bf16)v.z, (__bf16)v.w };
        *(bf16x4*)(xb + off) = s;
    }

    // ---- W_att panel (A-operand) + neighbor a-coefs (live for both tiles) ----
    bf16x8 bw[4][4];
    float cN[4][4];
#pragma unroll
    for (int c4 = 0; c4 < 4; ++c4) {
        int col = (w * 4 + c4) * 16 + lr;
#pragma unroll
        for (int ks = 0; ks < 4; ++ks)
            bw[c4][ks] = *(const bf16x8*)(WaT + col * 128 + ks * 32 + lg * 8);
#pragma unroll
        for (int i = 0; i < 4; ++i)
            cN[c4][i] = a[HH + (w * 4 + c4) * 16 + 4 * lg + i];
    }

    // score over neib rows (swapped operands; lane lr owns row rt*16+lr)
    auto SCORE_NEIB = [&]() {
#pragma unroll
        for (int rt = 0; rt < 8; ++rt) {
            bf16x8 af[4];
#pragma unroll
            for (int ks = 0; ks < 4; ++ks)
                af[ks] = *(const bf16x8*)(rb + abase[ks] + rt * 4096);
            f32x4 acc[4];
#pragma unroll
            for (int c4 = 0; c4 < 4; ++c4) acc[c4] = (f32x4){0.f, 0.f, 0.f, 0.f};
#pragma unroll
            for (int ks = 0; ks < 4; ++ks)
#pragma unroll
                for (int c4 = 0; c4 < 4; ++c4)
                    acc[c4] = __builtin_amdgcn_mfma_f32_16x16x32_bf16(bw[c4][ks], af[ks], acc[c4], 0, 0, 0);
            float ep = 0.f;
#pragma unroll
            for (int c4 = 0; c4 < 4; ++c4)
#pragma unroll
                for (int i = 0; i < 4; ++i) {
                    float v = acc[c4][i];
                    ep = fmaf(cN[c4][i], fmaxf(v, 0.01f * v), ep);
                }
            ep += __shfl_xor(ep, 16);
            ep += __shfl_xor(ep, 32);
            if (l < 16) e_part[w][rt * 16 + l] = ep;
        }
    };

    auto SOFTMAX = [&](int xrbase) {             // tid<128; node = tid>>5
        if (tid < 128) {
            const int bloc = tid >> 5;
            const int nloc = tid & 31;
            float sn = e_part[0][tid] + e_part[1][tid] + e_part[2][tid] + e_part[3][tid];
            int xr = xrbase + bloc;
            float sx = e_part[0][xr] + e_part[1][xr] + e_part[2][xr] + e_part[3][xr];
            float e = sx + sn;
            e = (e > 0.f) ? e : 0.2f * e;
            float mx = e;
#pragma unroll
            for (int m = 16; m >= 1; m >>= 1) mx = fmaxf(mx, __shfl_xor(mx, m, 32));
            float ex = __expf(e - mx);
            float sum = ex;
#pragma unroll
            for (int m = 16; m >= 1; m >>= 1) sum += __shfl_xor(sum, m, 32);
            att_s[bloc][nloc] = ex / sum;
        }
    };

    auto AGG = [&](int rowbase) {                // wave w = node w; writes xagg
        const int half = l >> 5, li = l & 31;
        const int agbase = w * 8192 + 256 * half + ((8 * li) ^ (half << 4));
        float ag[4] = {0.f, 0.f, 0.f, 0.f};
#pragma unroll
        for (int i = 0; i < 16; ++i) {
            float wv = att_s[w][2 * i + half];
            bf16x4 v = *(const bf16x4*)(rb + (agbase ^ ((2 * i & 7) << 4)) + 512 * i);
#pragma unroll
            for (int j = 0; j < 4; ++j) ag[j] = fmaf(wv, (float)v[j], ag[j]);
        }
#pragma unroll
        for (int j = 0; j < 4; ++j) ag[j] += __shfl_xor(ag[j], 32);
        if (half == 0) {
            int row = rowbase + w;               // (row&7) = 4+w for both tiles
            int off = row * 256 + ((8 * li) ^ ((row & 7) << 4));
            bf16x4 s = { (__bf16)ag[0], (__bf16)ag[1], (__bf16)ag[2], (__bf16)ag[3] };
            *(bf16x4*)(xb + off) = s;
        }
    };

    __syncthreads();                              // B1: tile0 + x rows staged

    SCORE_NEIB();                                 // tile0 -> e_part[w][0..127]
    {   // ONE peeled x-score over all 16 xagg rows (x0, junk, x1, junk)
        float cX[4][4];
#pragma unroll
        for (int c4 = 0; c4 < 4; ++c4)
#pragma unroll
            for (int i = 0; i < 4; ++i)
                cX[c4][i] = a[(w * 4 + c4) * 16 + 4 * lg + i];
        bf16x8 af[4];
#pragma unroll
        for (int ks = 0; ks < 4; ++ks)
            af[ks] = *(const bf16x8*)(xb + abase[ks]);
        f32x4 acc[4];
#pragma unroll
        for (int c4 = 0; c4 < 4; ++c4) acc[c4] = (f32x4){0.f, 0.f, 0.f, 0.f};
#pragma unroll
        for (int ks = 0; ks < 4; ++ks)
#pragma unroll
            for (int c4 = 0; c4 < 4; ++c4)
                acc[c4] = __builtin_amdgcn_mfma_f32_16x16x32_bf16(bw[c4][ks], af[ks], acc[c4], 0, 0, 0);
        float ep = 0.f;
#pragma unroll
        for (int c4 = 0; c4 < 4; ++c4)
#pragma unroll
            for (int i = 0; i < 4; ++i) {
                float v = acc[c4][i];
                ep = fmaf(cX[c4][i], fmaxf(v, 0.01f * v), ep);
            }
        ep += __shfl_xor(ep, 16);
        ep += __shfl_xor(ep, 32);
        if (l < 16) e_part[w][128 + l] = ep;      // 128..131=x0, 136..139=x1
    }
    __syncthreads();                              // B2: e_part complete

    SOFTMAX(128);                                 // tile0 softmax (x0)
    __syncthreads();                              // B3: att_s visible
    AGG(4);                                       // agg0 -> xagg rows 4..7
    __syncthreads();                              // B4: tile0 neib reads done

    // ---- stage tile1 (R13-style serial staging; no reg-held tile) ----
    {
        const float4* np4 = (const float4*)neibs + (size_t)(g0 + 1) * 4096;
#pragma unroll
        for (int it = 0; it < 16; ++it) {
            float4 v = np4[it * 256 + tid];
            bf16x4 s = { (__bf16)v.x, (__bf16)v.y, (__bf16)v.z, (__bf16)v.w };
            *(bf16x4*)(rb + stbase + it * 2048) = s;
        }
    }
    __syncthreads();                              // B5: tile1 staged

    SCORE_NEIB();                                 // tile1 -> e_part[w][0..127]
    __syncthreads();                              // B6

    SOFTMAX(136);                                 // tile1 softmax (x1 rows 8..11)

    // bff panel loads issue here; latency hides under agg1
    bf16x8 bff[4][4];
#pragma unroll
    for (int c4 = 0; c4 < 4; ++c4)
#pragma unroll
        for (int ks = 0; ks < 4; ++ks)
            bff[c4][ks] = *(const bf16x8*)(WcT + ((w * 4 + c4) * 16 + lr) * 128 + ks * 32 + lg * 8);

    __syncthreads();                              // B7: att_s (tile1) visible
    AGG(12);                                      // agg1 -> xagg rows 12..15
    __syncthreads();                              // B8: xagg complete

    // ---- final: [x0,agg0,x1,agg1](16x128) @ WcT^T(128x256), full util ----
    {
        bf16x8 af[4];
#pragma unroll
        for (int ks = 0; ks < 4; ++ks)
            af[ks] = *(const bf16x8*)(xb + abase[ks]);
        f32x4 acc[4];
#pragma unroll
        for (int c4 = 0; c4 < 4; ++c4) acc[c4] = (f32x4){0.f, 0.f, 0.f, 0.f};
#pragma unroll
        for (int ks = 0; ks < 4; ++ks)
#pragma unroll
            for (int c4 = 0; c4 < 4; ++c4)
                acc[c4] = __builtin_amdgcn_mfma_f32_16x16x32_bf16(af[ks], bff[c4][ks], acc[c4], 0, 0, 0);
#pragma unroll
        for (int c4 = 0; c4 < 4; ++c4) {
            int col = (w * 4 + c4) * 16 + lr;
#pragma unroll
            for (int reg = 0; reg < 4; ++reg) {
                int i = lg * 4 + reg;             // A row: i&4 ? agg : x; i>>3 = tile
                bool doit = ((col < 128) == ((i & 4) == 0));
                if (doit) {
                    int orow = b0 + (i & 3) + ((i >> 3) << 2);
                    out[(size_t)orow * 256 + col] = fmaxf(acc[c4][reg], 0.f);
                }
            }
        }
    }
}

extern "C" void kernel_launch(void* const* d_in, const int* in_sizes, int n_in,
                              void* d_out, int out_size, void* d_ws, size_t ws_size,
                              hipStream_t stream) {
    const float* x    = (const float*)d_in[0];
    const float* nb   = (const float*)d_in[1];
    const float* Watt = (const float*)d_in[2];
    const float* Wfcx = (const float*)d_in[3];
    const float* Wfcn = (const float*)d_in[4];
    const float* a    = (const float*)d_in[5];
    __bf16* WaT = (__bf16*)d_ws;
    __bf16* WcT = WaT + 32768;
    float* o = (float*)d_out;

    prep_weights<<<256, 256, 0, stream>>>(Watt, Wfcx, Wfcn, WaT, WcT);
    gat_fused<<<GRID, 256, 0, stream>>>(x, nb, a, WaT, WcT, o);
}